// Round 1
// baseline (574.021 us; speedup 1.0000x reference)
//
#include <hip/hip_runtime.h>

// Problem constants
#define NB   4      // batch
#define NN   4      // contexts per pixel
#define CCh  256    // Cc
#define CFh  512    // Cf
#define HH   128
#define WW   128
#define PLO  4096   // 64*64 low-res pixels
#define PHI  16384  // 128*128 hi-res pixels

typedef __bf16 bf16;
typedef __bf16 bf16x8 __attribute__((ext_vector_type(8)));
typedef float  f32x4  __attribute__((ext_vector_type(4)));

__device__ __forceinline__ void gll16(const void* g, void* lds) {
    __builtin_amdgcn_global_load_lds(
        (const __attribute__((address_space(1))) void*)g,
        (__attribute__((address_space(3))) void*)lds, 16, 0, 0);
}

// ---------------------------------------------------------------------------
// prep 1: M_qk[c][f] = sum_o Wc_w[o][c] * Wf_w[o][f]  (bf16 out)
//         d_qk[c]    = sum_o Wc_w[o][c] * Wf_b[o]     (fp32)
// grid (2, 256), block 256
__global__ void prep_mqk(const float* __restrict__ Wc_w, const float* __restrict__ Wf_w,
                         const float* __restrict__ Wf_b, bf16* __restrict__ M_qk,
                         float* __restrict__ d_qk) {
    int c = blockIdx.y;
    int f = blockIdx.x * 256 + threadIdx.x;
    float s = 0.f;
    for (int o = 0; o < CCh; ++o)
        s += Wc_w[o * CCh + c] * Wf_w[o * CFh + f];
    M_qk[c * CFh + f] = (bf16)s;
    if (blockIdx.x == 0 && threadIdx.x == 0) {
        float d = 0.f;
        for (int o = 0; o < CCh; ++o) d += Wc_w[o * CCh + c] * Wf_b[o];
        d_qk[c] = d;
    }
}

// ---------------------------------------------------------------------------
// prep 2: transpose mainstream [B][512][4096] fp32 -> ms_t [B][4096][512] bf16
// grid (128, 16, 4), block 256
__global__ void prep_ms(const float* __restrict__ ms, bf16* __restrict__ ms_t) {
    __shared__ float tile[32][33];
    int b = blockIdx.z;
    int p0 = blockIdx.x * 32, f0 = blockIdx.y * 32;
    int tx = threadIdx.x;
    int r = tx >> 5, cc = tx & 31;
    const float* src = ms + (size_t)b * CFh * PLO;
#pragma unroll
    for (int q = 0; q < 4; ++q) {
        int fl = q * 8 + r;
        tile[fl][cc] = src[(size_t)(f0 + fl) * PLO + p0 + cc];
    }
    __syncthreads();
    bf16* dst = ms_t + (size_t)b * PLO * CFh;
#pragma unroll
    for (int q = 0; q < 4; ++q) {
        int pl = q * 8 + r;
        dst[(size_t)(p0 + pl) * CFh + f0 + cc] = (bf16)tile[cc][pl];
    }
}

// ---------------------------------------------------------------------------
// prep 3: pack Wv_w [256][512][3][3] fp32 -> Wv_p [9][256][512] bf16; zero zerobuf
// grid (4608), block 256
__global__ void prep_wv(const float* __restrict__ Wv_w, bf16* __restrict__ Wv_p,
                        bf16* __restrict__ zerob) {
    int tid = blockIdx.x * 256 + threadIdx.x;   // t-major: (t*256 + c)*512 + f
    int t = tid / (CCh * CFh);
    int rem = tid % (CCh * CFh);
    int c = rem / CFh, f = rem % CFh;
    Wv_p[tid] = (bf16)Wv_w[(size_t)(c * CFh + f) * 9 + t];
    if (tid < 1024) zerob[tid] = (bf16)0.f;
}

// ---------------------------------------------------------------------------
// GEMM: out[c][p] = sum_taps sum_f W[t][c][f] * ms_t[shift_t(p)][f] + bias[c]
// mode 0 (conv, 9 taps) -> v_out ; mode 1 (qk, 1 tap) -> qk_out. bf16 outputs.
// M=channels(128-tile), N=pixels(128-tile), BK=32. 256 thr = 4 waves, 64x64/wave.
// grid (32, 2, 8): x=ptile, y=ctile, z = mode*4 + b
__global__ __launch_bounds__(256) void gemm_kernel(
    const bf16* __restrict__ Wv_p,   // [9][256][512]
    const bf16* __restrict__ M_qk,   // [256][512]
    const bf16* __restrict__ ms_t,   // [B][4096][512]
    const float* __restrict__ Wv_b, const float* __restrict__ d_qk,
    const bf16* __restrict__ zerob,
    bf16* __restrict__ v_out, bf16* __restrict__ qk_out) {
    __shared__ __align__(16) bf16 Alds[128 * 32];  // [c][f]
    __shared__ __align__(16) bf16 Blds[128 * 32];  // [p][f]

    const int tx = threadIdx.x;
    const int wave = tx >> 6, lane = tx & 63;
    const int ptile = blockIdx.x, ctile = blockIdx.y;
    const int b = blockIdx.z & 3, mode = blockIdx.z >> 2;

    const int ntaps = mode ? 1 : 9;
    const bf16* Wbase = mode ? M_qk : Wv_p;
    const float* bias = mode ? d_qk : Wv_b;
    bf16* obase = (mode ? qk_out : v_out) + (size_t)b * CCh * PLO;
    const bf16* msb = ms_t + (size_t)b * PLO * CFh;

    // staging lane mapping: issue q covers bytes [wave*2048 + q*1024, +1024)
    int idx0 = wave * 2048 + lane * 16;
    int idx1 = idx0 + 1024;
    int rA0 = idx0 >> 6, fq0 = (idx0 >> 4) & 3;   // row 0..127, 16B-chunk 0..3
    int rA1 = idx1 >> 6, fq1 = (idx1 >> 4) & 3;
    const size_t aoff0 = (size_t)(ctile * 128 + rA0) * CFh + fq0 * 8;
    const size_t aoff1 = (size_t)(ctile * 128 + rA1) * CFh + fq1 * 8;
    char* ldsA0 = (char*)Alds + wave * 2048;
    char* ldsA1 = ldsA0 + 1024;
    char* ldsB0 = (char*)Blds + wave * 2048;
    char* ldsB1 = ldsB0 + 1024;

    const int p0 = ptile * 128 + rA0, p1 = ptile * 128 + rA1;
    const int i0 = p0 >> 6, j0 = p0 & 63;
    const int i1 = p1 >> 6, j1 = p1 & 63;

    f32x4 acc[4][4];
#pragma unroll
    for (int mi = 0; mi < 4; ++mi)
#pragma unroll
        for (int ni = 0; ni < 4; ++ni) acc[mi][ni] = f32x4{0.f, 0.f, 0.f, 0.f};

    const int wm = wave >> 1, wn = wave & 1;
    const int quad = lane >> 4, l15 = lane & 15;

    for (int t = 0; t < ntaps; ++t) {
        const int dy = mode ? 0 : (t / 3 - 1);
        const int dx = mode ? 0 : (t % 3 - 1);
        const bf16* Wt = Wbase + (size_t)(mode ? 0 : t) * CCh * CFh;
        int si0 = i0 + dy, sj0 = j0 + dx, si1 = i1 + dy, sj1 = j1 + dx;
        bool ok0 = (unsigned)si0 < 64u && (unsigned)sj0 < 64u;
        bool ok1 = (unsigned)si1 < 64u && (unsigned)sj1 < 64u;
        const bf16* bsrc0 = ok0 ? msb + (size_t)(si0 * 64 + sj0) * CFh + fq0 * 8 : zerob;
        const bf16* bsrc1 = ok1 ? msb + (size_t)(si1 * 64 + sj1) * CFh + fq1 * 8 : zerob;

        for (int fc = 0; fc < CFh / 32; ++fc) {
            const int f0 = fc * 32;
            __syncthreads();   // prev compute done before overwriting LDS
            gll16(Wt + aoff0 + f0, ldsA0);
            gll16(Wt + aoff1 + f0, ldsA1);
            gll16(bsrc0 + f0, ldsB0);
            gll16(bsrc1 + f0, ldsB1);
            __syncthreads();   // compiler inserts vmcnt(0) drain before barrier

            bf16x8 af[4], bfr[4];
#pragma unroll
            for (int mi = 0; mi < 4; ++mi)
                af[mi] = *(const bf16x8*)&Alds[(wm * 64 + mi * 16 + l15) * 32 + quad * 8];
#pragma unroll
            for (int ni = 0; ni < 4; ++ni)
                bfr[ni] = *(const bf16x8*)&Blds[(wn * 64 + ni * 16 + l15) * 32 + quad * 8];
#pragma unroll
            for (int mi = 0; mi < 4; ++mi)
#pragma unroll
                for (int ni = 0; ni < 4; ++ni)
                    acc[mi][ni] = __builtin_amdgcn_mfma_f32_16x16x32_bf16(
                        af[mi], bfr[ni], acc[mi][ni], 0, 0, 0);
        }
    }

    // C/D layout: col = lane&15 (pixel), row = quad*4 + r (channel)
#pragma unroll
    for (int mi = 0; mi < 4; ++mi) {
        int cb = ctile * 128 + wm * 64 + mi * 16 + quad * 4;
#pragma unroll
        for (int ni = 0; ni < 4; ++ni) {
            int p = ptile * 128 + wn * 64 + ni * 16 + l15;
            bf16* op = obase + (size_t)cb * PLO + p;
#pragma unroll
            for (int r = 0; r < 4; ++r)
                op[(size_t)r * PLO] = (bf16)(acc[mi][ni][r] + bias[cb + r]);
        }
    }
}

// ---------------------------------------------------------------------------
// attention: per hi-res pixel: scores over N via qk_up, softmax, weighted ctx
// sum + v_up. Block = 256 thr = 64 pixels x 4 channel-chunks. grid (1024).
__global__ __launch_bounds__(256) void attn_kernel(
    const float* __restrict__ ctx,   // [4][4][256][128][128]
    const bf16* __restrict__ qk,     // [4][256][4096]
    const bf16* __restrict__ v,      // [4][256][4096]
    float* __restrict__ out) {       // [4][256][128][128]
    __shared__ float sred[4][64][4];
    const size_t NSTR = (size_t)CCh * PHI;   // stride between n
    int tx = threadIdx.x;
    int pxl = tx & 63, cc = tx >> 6;
    int pbase = blockIdx.x << 6;
    int b = pbase >> 14;
    int rem = pbase & 16383;
    int hh = rem >> 7, w0 = rem & 127;
    int wwp = w0 + pxl;
    int i = hh >> 1, j = wwp >> 1;

    const size_t cbase = (size_t)b * NN * CCh * PHI + hh * WW + wwp;
    const bf16* qkb = qk + (size_t)b * CCh * PLO + i * 64 + j;
    const bf16* vb  = v  + (size_t)b * CCh * PLO + i * 64 + j;
    const int c0 = cc * 64;

    float s0 = 0.f, s1 = 0.f, s2 = 0.f, s3 = 0.f;
#pragma unroll 8
    for (int ci = 0; ci < 64; ++ci) {
        int c = c0 + ci;
        float q = (float)qkb[(size_t)c * PLO];
        size_t base = cbase + (size_t)c * PHI;
        s0 += ctx[base] * q;
        s1 += ctx[base + NSTR] * q;
        s2 += ctx[base + 2 * NSTR] * q;
        s3 += ctx[base + 3 * NSTR] * q;
    }
    sred[cc][pxl][0] = s0; sred[cc][pxl][1] = s1;
    sred[cc][pxl][2] = s2; sred[cc][pxl][3] = s3;
    __syncthreads();
    float t0 = sred[0][pxl][0] + sred[1][pxl][0] + sred[2][pxl][0] + sred[3][pxl][0];
    float t1 = sred[0][pxl][1] + sred[1][pxl][1] + sred[2][pxl][1] + sred[3][pxl][1];
    float t2 = sred[0][pxl][2] + sred[1][pxl][2] + sred[2][pxl][2] + sred[3][pxl][2];
    float t3 = sred[0][pxl][3] + sred[1][pxl][3] + sred[2][pxl][3] + sred[3][pxl][3];
    float m = fmaxf(fmaxf(t0, t1), fmaxf(t2, t3));
    float e0 = __expf(t0 - m), e1 = __expf(t1 - m), e2 = __expf(t2 - m), e3 = __expf(t3 - m);
    float inv = 1.f / (e0 + e1 + e2 + e3);
    float a0 = e0 * inv, a1 = e1 * inv, a2 = e2 * inv, a3 = e3 * inv;

    float* ob = out + ((size_t)b * CCh) * PHI + hh * WW + wwp;
#pragma unroll 8
    for (int ci = 0; ci < 64; ++ci) {
        int c = c0 + ci;
        size_t base = cbase + (size_t)c * PHI;
        float acc = (float)vb[(size_t)c * PLO];
        acc += ctx[base] * a0 + ctx[base + NSTR] * a1 +
               ctx[base + 2 * NSTR] * a2 + ctx[base + 3 * NSTR] * a3;
        ob[(size_t)c * PHI] = acc;
    }
}

// ---------------------------------------------------------------------------
extern "C" void kernel_launch(void* const* d_in, const int* in_sizes, int n_in,
                              void* d_out, int out_size, void* d_ws, size_t ws_size,
                              hipStream_t stream) {
    const float* ctx  = (const float*)d_in[0];
    const float* ms   = (const float*)d_in[1];
    const float* Wc_w = (const float*)d_in[2];
    // d_in[3] = Wc_b: constant across n at each pixel -> cancels in softmax.
    const float* Wf_w = (const float*)d_in[4];
    const float* Wf_b = (const float*)d_in[5];
    const float* Wv_w = (const float*)d_in[6];
    const float* Wv_b = (const float*)d_in[7];
    float* out = (float*)d_out;

    char* ws = (char*)d_ws;
    bf16*  ms_t = (bf16*)ws;                      // 16,777,216 B
    bf16*  Wv_p = (bf16*)(ws + 16777216);         //  2,359,296 B
    bf16*  M_qk = (bf16*)(ws + 19136512);         //    262,144 B
    float* d_qk = (float*)(ws + 19398656);        //      1,024 B
    bf16*  zerob = (bf16*)(ws + 19399680);        //      2,048 B
    bf16*  qk   = (bf16*)(ws + 19401728);         //  8,388,608 B
    bf16*  v    = (bf16*)(ws + 27790336);         //  8,388,608 B  (total ~34.5 MB)

    prep_mqk<<<dim3(2, 256), 256, 0, stream>>>(Wc_w, Wf_w, Wf_b, M_qk, d_qk);
    prep_ms<<<dim3(128, 16, 4), 256, 0, stream>>>(ms, ms_t);
    prep_wv<<<dim3(4608), 256, 0, stream>>>(Wv_w, Wv_p, zerob);
    gemm_kernel<<<dim3(32, 2, 8), 256, 0, stream>>>(Wv_p, M_qk, ms_t, Wv_b, d_qk,
                                                    zerob, v, qk);
    attn_kernel<<<dim3(1024), 256, 0, stream>>>(ctx, qk, v, out);
}

// Round 2
// 513.213 us; speedup vs baseline: 1.1185x; 1.1185x over previous
//
#include <hip/hip_runtime.h>

// Problem constants
#define NB   4      // batch
#define NN   4      // contexts per pixel
#define CCh  256    // Cc
#define CFh  512    // Cf
#define HH   128
#define WW   128
#define PLO  4096   // 64*64 low-res pixels
#define PHI  16384  // 128*128 hi-res pixels

typedef __bf16 bf16;
typedef __bf16 bf16x8 __attribute__((ext_vector_type(8)));
typedef float  f32x4  __attribute__((ext_vector_type(4)));
typedef float  f32x2  __attribute__((ext_vector_type(2)));

__device__ __forceinline__ void gll16(const void* g, void* lds) {
    __builtin_amdgcn_global_load_lds(
        (const __attribute__((address_space(1))) void*)g,
        (__attribute__((address_space(3))) void*)lds, 16, 0, 0);
}

// ---------------------------------------------------------------------------
// prep 1: M_qk[c][f] = sum_o Wc_w[o][c] * Wf_w[o][f]  (bf16 out)
//         d_qk[c]    = sum_o Wc_w[o][c] * Wf_b[o]     (fp32)
__global__ void prep_mqk(const float* __restrict__ Wc_w, const float* __restrict__ Wf_w,
                         const float* __restrict__ Wf_b, bf16* __restrict__ M_qk,
                         float* __restrict__ d_qk) {
    int c = blockIdx.y;
    int f = blockIdx.x * 256 + threadIdx.x;
    float s = 0.f;
    for (int o = 0; o < CCh; ++o)
        s += Wc_w[o * CCh + c] * Wf_w[o * CFh + f];
    M_qk[c * CFh + f] = (bf16)s;
    if (blockIdx.x == 0 && threadIdx.x == 0) {
        float d = 0.f;
        for (int o = 0; o < CCh; ++o) d += Wc_w[o * CCh + c] * Wf_b[o];
        d_qk[c] = d;
    }
}

// ---------------------------------------------------------------------------
// prep 2: transpose mainstream [B][512][4096] fp32 -> ms_t [B][4096][512] bf16
__global__ void prep_ms(const float* __restrict__ ms, bf16* __restrict__ ms_t) {
    __shared__ float tile[32][33];
    int b = blockIdx.z;
    int p0 = blockIdx.x * 32, f0 = blockIdx.y * 32;
    int tx = threadIdx.x;
    int r = tx >> 5, cc = tx & 31;
    const float* src = ms + (size_t)b * CFh * PLO;
#pragma unroll
    for (int q = 0; q < 4; ++q) {
        int fl = q * 8 + r;
        tile[fl][cc] = src[(size_t)(f0 + fl) * PLO + p0 + cc];
    }
    __syncthreads();
    bf16* dst = ms_t + (size_t)b * PLO * CFh;
#pragma unroll
    for (int q = 0; q < 4; ++q) {
        int pl = q * 8 + r;
        dst[(size_t)(p0 + pl) * CFh + f0 + cc] = (bf16)tile[cc][pl];
    }
}

// ---------------------------------------------------------------------------
// prep 3: pack Wv_w [256][512][3][3] fp32 -> Wv_p [9][256][512] bf16; zero zerobuf
__global__ void prep_wv(const float* __restrict__ Wv_w, bf16* __restrict__ Wv_p,
                        bf16* __restrict__ zerob) {
    int tid = blockIdx.x * 256 + threadIdx.x;   // t-major: (t*256 + c)*512 + f
    int t = tid / (CCh * CFh);
    int rem = tid % (CCh * CFh);
    int c = rem / CFh, f = rem % CFh;
    Wv_p[tid] = (bf16)Wv_w[(size_t)(c * CFh + f) * 9 + t];
    if (tid < 1024) zerob[tid] = (bf16)0.f;
}

// ---------------------------------------------------------------------------
// GEMM: M=channels(128-tile), N=pixels(128-tile), BK=32, 256 thr = 4 waves.
// grid (32, 2, 16): z<12 -> conv tap-group tg=z%3, b=z/3, taps [3tg,3tg+3),
//   writes fp32 partials (no bias) to v3[tg][b][256][4096].
// z>=12 -> qk (1 tap), b=z-12, writes bf16 (+d_qk bias) to qk_out.
__global__ __launch_bounds__(256) void gemm_kernel(
    const bf16* __restrict__ Wv_p,   // [9][256][512]
    const bf16* __restrict__ M_qk,   // [256][512]
    const bf16* __restrict__ ms_t,   // [B][4096][512]
    const float* __restrict__ d_qk,
    const bf16* __restrict__ zerob,
    float* __restrict__ v3, bf16* __restrict__ qk_out) {
    __shared__ __align__(16) bf16 Alds[128 * 32];  // [c][f]
    __shared__ __align__(16) bf16 Blds[128 * 32];  // [p][f]

    const int tx = threadIdx.x;
    const int wave = tx >> 6, lane = tx & 63;
    const int ptile = blockIdx.x, ctile = blockIdx.y;
    const int z = blockIdx.z;
    const int mode = (z >= 12);                 // 0=conv partial, 1=qk
    const int b = mode ? (z - 12) : (z / 3);
    const int tg = mode ? 0 : (z % 3);
    const int t0 = tg * 3;
    const int ntaps = mode ? 1 : 3;

    const bf16* Wbase = mode ? M_qk : (Wv_p + (size_t)t0 * CCh * CFh);
    const bf16* msb = ms_t + (size_t)b * PLO * CFh;

    // staging lane mapping: issue q covers bytes [wave*2048 + q*1024, +1024)
    int idx0 = wave * 2048 + lane * 16;
    int idx1 = idx0 + 1024;
    int rA0 = idx0 >> 6, fq0 = (idx0 >> 4) & 3;   // row 0..127, 16B-chunk 0..3
    int rA1 = idx1 >> 6, fq1 = (idx1 >> 4) & 3;
    const size_t aoff0 = (size_t)(ctile * 128 + rA0) * CFh + fq0 * 8;
    const size_t aoff1 = (size_t)(ctile * 128 + rA1) * CFh + fq1 * 8;
    char* ldsA0 = (char*)Alds + wave * 2048;
    char* ldsA1 = ldsA0 + 1024;
    char* ldsB0 = (char*)Blds + wave * 2048;
    char* ldsB1 = ldsB0 + 1024;

    const int p0 = ptile * 128 + rA0, p1 = ptile * 128 + rA1;
    const int i0 = p0 >> 6, j0 = p0 & 63;
    const int i1 = p1 >> 6, j1 = p1 & 63;

    f32x4 acc[4][4];
#pragma unroll
    for (int mi = 0; mi < 4; ++mi)
#pragma unroll
        for (int ni = 0; ni < 4; ++ni) acc[mi][ni] = f32x4{0.f, 0.f, 0.f, 0.f};

    const int wm = wave >> 1, wn = wave & 1;
    const int quad = lane >> 4, l15 = lane & 15;

    for (int t = 0; t < ntaps; ++t) {
        const int dy = mode ? 0 : ((t0 + t) / 3 - 1);
        const int dx = mode ? 0 : ((t0 + t) % 3 - 1);
        const bf16* Wt = Wbase + (size_t)t * CCh * CFh;
        int si0 = i0 + dy, sj0 = j0 + dx, si1 = i1 + dy, sj1 = j1 + dx;
        bool ok0 = (unsigned)si0 < 64u && (unsigned)sj0 < 64u;
        bool ok1 = (unsigned)si1 < 64u && (unsigned)sj1 < 64u;
        const bf16* bsrc0 = ok0 ? msb + (size_t)(si0 * 64 + sj0) * CFh + fq0 * 8 : zerob;
        const bf16* bsrc1 = ok1 ? msb + (size_t)(si1 * 64 + sj1) * CFh + fq1 * 8 : zerob;

        for (int fc = 0; fc < CFh / 32; ++fc) {
            const int f0 = fc * 32;
            __syncthreads();   // prev compute done before overwriting LDS
            gll16(Wt + aoff0 + f0, ldsA0);
            gll16(Wt + aoff1 + f0, ldsA1);
            gll16(bsrc0 + f0, ldsB0);
            gll16(bsrc1 + f0, ldsB1);
            __syncthreads();

            bf16x8 af[4], bfr[4];
#pragma unroll
            for (int mi = 0; mi < 4; ++mi)
                af[mi] = *(const bf16x8*)&Alds[(wm * 64 + mi * 16 + l15) * 32 + quad * 8];
#pragma unroll
            for (int ni = 0; ni < 4; ++ni)
                bfr[ni] = *(const bf16x8*)&Blds[(wn * 64 + ni * 16 + l15) * 32 + quad * 8];
#pragma unroll
            for (int mi = 0; mi < 4; ++mi)
#pragma unroll
                for (int ni = 0; ni < 4; ++ni)
                    acc[mi][ni] = __builtin_amdgcn_mfma_f32_16x16x32_bf16(
                        af[mi], bfr[ni], acc[mi][ni], 0, 0, 0);
        }
    }

    // C/D layout: col = lane&15 (pixel), row = quad*4 + r (channel)
    if (mode) {
        bf16* obase = qk_out + (size_t)b * CCh * PLO;
#pragma unroll
        for (int mi = 0; mi < 4; ++mi) {
            int cb = ctile * 128 + wm * 64 + mi * 16 + quad * 4;
#pragma unroll
            for (int ni = 0; ni < 4; ++ni) {
                int p = ptile * 128 + wn * 64 + ni * 16 + l15;
                bf16* op = obase + (size_t)cb * PLO + p;
#pragma unroll
                for (int r = 0; r < 4; ++r)
                    op[(size_t)r * PLO] = (bf16)(acc[mi][ni][r] + d_qk[cb + r]);
            }
        }
    } else {
        float* obase = v3 + (size_t)(tg * NB + b) * CCh * PLO;
#pragma unroll
        for (int mi = 0; mi < 4; ++mi) {
            int cb = ctile * 128 + wm * 64 + mi * 16 + quad * 4;
#pragma unroll
            for (int ni = 0; ni < 4; ++ni) {
                int p = ptile * 128 + wn * 64 + ni * 16 + l15;
                float* op = obase + (size_t)cb * PLO + p;
#pragma unroll
                for (int r = 0; r < 4; ++r)
                    op[(size_t)r * PLO] = acc[mi][ni][r];
            }
        }
    }
}

// ---------------------------------------------------------------------------
// attention, single ctx pass: block = 512 thr, 64 pixels (one 64-wide w strip).
// Thread: 4 consecutive w-pixels (f32x4 lanes) x 8 channels x 4 n held in VGPRs.
// Phase 1: load ctx (dwordx4) + dot with qk. Phase 2: shfl+LDS reduce, softmax.
// Phase 3: weighted sum from VGPRs + conv partials + bias -> out.
__global__ __launch_bounds__(512) void attn_kernel(
    const float* __restrict__ ctx,   // [4][4][256][128][128]
    const bf16* __restrict__ qk,     // [4][256][4096]
    const float* __restrict__ v3,    // [3][4][256][4096] conv partials
    const float* __restrict__ Wv_b,  // [256]
    float* __restrict__ out) {       // [4][256][128][128]
    __shared__ f32x4 swred[4][8][16];  // [n][wave][pq]
    const int tx = threadIdx.x;
    const int pq = tx & 15;            // which 4-pixel group
    const int cc = tx >> 4;            // channel chunk 0..31
    const int lane = tx & 63;
    const int wv = tx >> 6;
    const int quad = lane >> 4;

    const int pbase = blockIdx.x << 6;
    const int b = pbase >> 14;
    const int rem = pbase & 16383;
    const int hh = rem >> 7;
    const int w0 = rem & 127;          // 0 or 64
    const int wq = w0 + pq * 4;
    const int i = hh >> 1, j0 = wq >> 1;   // j0 even

    const int c0 = cc * 8;
    const size_t NSTR = (size_t)CCh * PHI;
    const float* cbase = ctx + (size_t)b * NN * NSTR + (size_t)c0 * PHI
                             + (size_t)hh * WW + wq;
    const bf16* qkb = qk + ((size_t)b * CCh + c0) * PLO + i * 64 + j0;
    const float* vbp = v3 + ((size_t)b * CCh + c0) * PLO + i * 64 + j0;

    f32x4 vals[4][8];
    f32x4 s[4];
#pragma unroll
    for (int n = 0; n < 4; ++n) s[n] = f32x4{0.f, 0.f, 0.f, 0.f};

#pragma unroll
    for (int cj = 0; cj < 8; ++cj) {
        unsigned qw = *(const unsigned*)(qkb + (size_t)cj * PLO);
        float qa = __uint_as_float(qw << 16);
        float qb = __uint_as_float(qw & 0xffff0000u);
        f32x4 qv = {qa, qa, qb, qb};
#pragma unroll
        for (int n = 0; n < 4; ++n) {
            vals[n][cj] = *(const f32x4*)(cbase + n * NSTR + (size_t)cj * PHI);
            s[n] += vals[n][cj] * qv;
        }
    }
    // reduce over the 4 quads within each wave (cc bits 0..1 live in lane bits 4..5)
#pragma unroll
    for (int n = 0; n < 4; ++n) {
#pragma unroll
        for (int m = 16; m <= 32; m <<= 1) {
            f32x4 t;
            t[0] = __shfl_xor(s[n][0], m);
            t[1] = __shfl_xor(s[n][1], m);
            t[2] = __shfl_xor(s[n][2], m);
            t[3] = __shfl_xor(s[n][3], m);
            s[n] += t;
        }
    }
    // lane with quad q publishes n=q for its wave
    f32x4 sq = (quad == 0) ? s[0] : (quad == 1) ? s[1] : (quad == 2) ? s[2] : s[3];
    swred[quad][wv][pq] = sq;
    __syncthreads();

    f32x4 t4[4];
#pragma unroll
    for (int n = 0; n < 4; ++n) {
        f32x4 a = swred[n][0][pq];
#pragma unroll
        for (int w = 1; w < 8; ++w) a += swred[n][w][pq];
        t4[n] = a;
    }
    f32x4 mx;
#pragma unroll
    for (int k = 0; k < 4; ++k)
        mx[k] = fmaxf(fmaxf(t4[0][k], t4[1][k]), fmaxf(t4[2][k], t4[3][k]));
    f32x4 e[4];
#pragma unroll
    for (int n = 0; n < 4; ++n)
#pragma unroll
        for (int k = 0; k < 4; ++k) e[n][k] = __expf(t4[n][k] - mx[k]);
    f32x4 ssum = e[0] + e[1] + e[2] + e[3];
    f32x4 a4[4];
#pragma unroll
    for (int n = 0; n < 4; ++n)
#pragma unroll
        for (int k = 0; k < 4; ++k) a4[n][k] = e[n][k] / ssum[k];

    float* outp = out + ((size_t)b * CCh + c0) * PHI + (size_t)hh * WW + wq;
#pragma unroll
    for (int cj = 0; cj < 8; ++cj) {
        f32x2 vv = *(const f32x2*)(vbp + (size_t)cj * PLO);
        vv += *(const f32x2*)(vbp + 4194304 + (size_t)cj * PLO);
        vv += *(const f32x2*)(vbp + 8388608 + (size_t)cj * PLO);
        float bc = Wv_b[c0 + cj];
        float va = vv[0] + bc, vb2 = vv[1] + bc;
        f32x4 o = vals[0][cj] * a4[0] + vals[1][cj] * a4[1] +
                  vals[2][cj] * a4[2] + vals[3][cj] * a4[3] +
                  f32x4{va, va, vb2, vb2};
        *(f32x4*)(outp + (size_t)cj * PHI) = o;
    }
}

// ---------------------------------------------------------------------------
extern "C" void kernel_launch(void* const* d_in, const int* in_sizes, int n_in,
                              void* d_out, int out_size, void* d_ws, size_t ws_size,
                              hipStream_t stream) {
    const float* ctx  = (const float*)d_in[0];
    const float* ms   = (const float*)d_in[1];
    const float* Wc_w = (const float*)d_in[2];
    // d_in[3] = Wc_b: constant across n at each pixel -> cancels in softmax.
    const float* Wf_w = (const float*)d_in[4];
    const float* Wf_b = (const float*)d_in[5];
    const float* Wv_w = (const float*)d_in[6];
    const float* Wv_b = (const float*)d_in[7];
    float* out = (float*)d_out;

    char* ws = (char*)d_ws;
    bf16*  ms_t  = (bf16*)ws;                     // 16,777,216 B
    bf16*  Wv_p  = (bf16*)(ws + 16777216);        //  2,359,296 B
    bf16*  M_qk  = (bf16*)(ws + 19136512);        //    262,144 B
    float* d_qk  = (float*)(ws + 19398656);       //      1,024 B
    bf16*  zerob = (bf16*)(ws + 19399680);        //      2,048 B
    bf16*  qk    = (bf16*)(ws + 19401728);        //  8,388,608 B
    float* v3    = (float*)(ws + 27790336);       // 50,331,648 B (total ~78.1 MB)

    prep_mqk<<<dim3(2, 256), 256, 0, stream>>>(Wc_w, Wf_w, Wf_b, M_qk, d_qk);
    prep_ms<<<dim3(128, 16, 4), 256, 0, stream>>>(ms, ms_t);
    prep_wv<<<dim3(4608), 256, 0, stream>>>(Wv_w, Wv_p, zerob);
    gemm_kernel<<<dim3(32, 2, 16), 256, 0, stream>>>(Wv_p, M_qk, ms_t, d_qk,
                                                     zerob, v3, qk);
    attn_kernel<<<dim3(1024), 512, 0, stream>>>(ctx, qk, v3, Wv_b, out);
}